// Round 11
// baseline (720.119 us; speedup 1.0000x reference)
//
#include <hip/hip_runtime.h>
#include <hip/hip_bf16.h>
#include <cstdint>
#include <cstddef>

#define N_NODES 50000
#define N_EDGES 800000
#define NSEG    (N_NODES * 8)            // 400000 (et,dst) buckets

using frag_t = __attribute__((ext_vector_type(8))) short;   // 8 bf16 (4 VGPRs)
using f32x4  = __attribute__((ext_vector_type(4))) float;   // 4 fp32 acc

typedef const __attribute__((address_space(1))) void* gptr_t;
typedef __attribute__((address_space(3))) void* lptr_t;

__device__ __forceinline__ short f2bf(float x) {
    __hip_bfloat16 h = __float2bfloat16(x);
    return *reinterpret_cast<short*>(&h);
}
__device__ __forceinline__ float bf2f(unsigned int u) {   // low 16 bits = bf16
    union { unsigned int i; float f; } v;
    v.i = u << 16;
    return v.f;
}
__device__ __forceinline__ unsigned int packbf2(float lo, float hi) {
    unsigned int a = (unsigned short)f2bf(lo);
    unsigned int b = (unsigned short)f2bf(hi);
    return a | (b << 16);
}

// ============================ CSR build over (et*N + dst) — relation-major ============================

__global__ void hist_kernel(const int* __restrict__ dst, const int* __restrict__ et,
                            int* __restrict__ deg2, int E) {
    int e = blockIdx.x * 256 + threadIdx.x;
    if (e < E) atomicAdd(&deg2[et[e] * N_NODES + dst[e]], 1);
}

__global__ __launch_bounds__(256) void scan_part(const int* __restrict__ deg2,
                                                 int* __restrict__ part, int M) {
    __shared__ int red[256];
    int t = threadIdx.x;
    int idx = blockIdx.x * 1024 + t * 4;
    int s = 0;
    if (idx + 3 < M) {
        int4 d = *(const int4*)(deg2 + idx);
        s = d.x + d.y + d.z + d.w;
    } else {
        for (int c = 0; c < 4; c++) if (idx + c < M) s += deg2[idx + c];
    }
    red[t] = s;
    __syncthreads();
    #pragma unroll
    for (int off = 128; off; off >>= 1) {
        if (t < off) red[t] += red[t + off];
        __syncthreads();
    }
    if (t == 0) part[blockIdx.x] = red[0];
}

__global__ __launch_bounds__(512) void scan_mid(int* __restrict__ part, int nparts,
                                                int* __restrict__ rowp, int M) {
    __shared__ int buf[512];
    int t = threadIdx.x;
    int own = (t < nparts) ? part[t] : 0;
    buf[t] = own;
    __syncthreads();
    for (int off = 1; off < 512; off <<= 1) {
        int v = buf[t];
        int u = (t >= off) ? buf[t - off] : 0;
        __syncthreads();
        buf[t] = v + u;
        __syncthreads();
    }
    if (t < nparts) part[t] = buf[t] - own;    // exclusive
    if (t == 511) rowp[M] = buf[511];          // total
}

__global__ __launch_bounds__(256) void scan_fix(const int* __restrict__ deg2,
                                                const int* __restrict__ part,
                                                int* __restrict__ rowp,
                                                int* __restrict__ cursor, int M) {
    __shared__ int wsum[4];
    int t = threadIdx.x, lane = t & 63, w = t >> 6;
    int idx = blockIdx.x * 1024 + t * 4;
    int v0 = 0, v1 = 0, v2 = 0, v3 = 0;
    if (idx + 3 < M) {
        int4 d = *(const int4*)(deg2 + idx);
        v0 = d.x; v1 = d.y; v2 = d.z; v3 = d.w;
    } else {
        if (idx     < M) v0 = deg2[idx];
        if (idx + 1 < M) v1 = deg2[idx + 1];
        if (idx + 2 < M) v2 = deg2[idx + 2];
        if (idx + 3 < M) v3 = deg2[idx + 3];
    }
    int tsum = v0 + v1 + v2 + v3;
    int sc = tsum;
    #pragma unroll
    for (int off = 1; off < 64; off <<= 1) {
        int u = __shfl_up(sc, off, 64);
        if (lane >= off) sc += u;
    }
    if (lane == 63) wsum[w] = sc;
    __syncthreads();
    int woff = 0;
    for (int i = 0; i < w; i++) woff += wsum[i];
    int excl = part[blockIdx.x] + woff + sc - tsum;
    if (idx     < M) { rowp[idx]     = excl; cursor[idx]     = excl; } excl += v0;
    if (idx + 1 < M) { rowp[idx + 1] = excl; cursor[idx + 1] = excl; } excl += v1;
    if (idx + 2 < M) { rowp[idx + 2] = excl; cursor[idx + 2] = excl; } excl += v2;
    if (idx + 3 < M) { rowp[idx + 3] = excl; cursor[idx + 3] = excl; }
}

// sorted2 packs src | dst<<16 (both < 65536); et implicit from position.
// NOTE: decode the dst field with an UNSIGNED shift — dst>=32768 sets the sign bit.
__global__ void fill_kernel(const int* __restrict__ src, const int* __restrict__ dst,
                            const int* __restrict__ et, int* __restrict__ cursor,
                            int* __restrict__ sorted2, int E) {
    int e = blockIdx.x * 256 + threadIdx.x;
    if (e < E) {
        int pos = atomicAdd(&cursor[et[e] * N_NODES + dst[e]], 1);
        sorted2[pos] = src[e] | (dst[e] << 16);
    }
}

// ============================ fp32 tiled GEMM (linear layer, K=64) -> bf16 hb ============================

__global__ __launch_bounds__(256) void gemm_lin(const float* __restrict__ A,
                                                const float* __restrict__ B,
                                                const float* __restrict__ bias,
                                                unsigned short* __restrict__ hb, int N) {
    const int Kdim = 64;
    __shared__ float As[32][64];
    __shared__ float Bs[32][128];
    int t = threadIdx.x;
    int n0 = blockIdx.x * 64;
    int rg = t >> 4, cg = t & 15;
    int an = t >> 2, ak = (t & 3) * 8;
    float acc[4][8] = {};

    for (int k0 = 0; k0 < Kdim; k0 += 32) {
        int gn = n0 + an;
        if (gn < N) {
            const float* ap = A + (size_t)gn * Kdim + k0 + ak;
            float4 v0 = *(const float4*)ap;
            float4 v1 = *(const float4*)(ap + 4);
            As[ak + 0][an] = v0.x; As[ak + 1][an] = v0.y;
            As[ak + 2][an] = v0.z; As[ak + 3][an] = v0.w;
            As[ak + 4][an] = v1.x; As[ak + 5][an] = v1.y;
            As[ak + 6][an] = v1.z; As[ak + 7][an] = v1.w;
        } else {
            #pragma unroll
            for (int c = 0; c < 8; c++) As[ak + c][an] = 0.f;
        }
        {
            int o = t >> 1, kh = (t & 1) * 16;
            const float* bp = B + (size_t)o * Kdim + k0 + kh;
            #pragma unroll
            for (int j = 0; j < 4; j++) {
                float4 v = ((const float4*)bp)[j];
                Bs[kh + j * 4 + 0][o] = v.x;
                Bs[kh + j * 4 + 1][o] = v.y;
                Bs[kh + j * 4 + 2][o] = v.z;
                Bs[kh + j * 4 + 3][o] = v.w;
            }
        }
        __syncthreads();
        #pragma unroll
        for (int k = 0; k < 32; k++) {
            float a[4], b[8];
            *(float4*)&a[0] = *(const float4*)&As[k][rg * 4];
            *(float4*)&b[0] = *(const float4*)&Bs[k][cg * 8];
            *(float4*)&b[4] = *(const float4*)&Bs[k][cg * 8 + 4];
            #pragma unroll
            for (int i = 0; i < 4; i++)
                #pragma unroll
                for (int j = 0; j < 8; j++)
                    acc[i][j] = fmaf(a[i], b[j], acc[i][j]);
        }
        __syncthreads();
    }
    #pragma unroll
    for (int i = 0; i < 4; i++) {
        int gn = n0 + rg * 4 + i;
        if (gn < N) {
            unsigned short us[8];
            #pragma unroll
            for (int j = 0; j < 8; j++)
                us[j] = (unsigned short)f2bf(acc[i][j] + bias[cg * 8 + j]);
            *(int4*)(hb + (size_t)gn * 128 + cg * 8) = *(int4*)&us[0];
        }
    }
}

// ============================ merged W prep: Bf convert + wq/wk ============================

__global__ void wprep_kernel(const float* __restrict__ W, const float* __restrict__ q,
                             const float* __restrict__ k, short* __restrict__ Bf,
                             float* __restrict__ wq, float* __restrict__ wk) {
    int g = blockIdx.x * 256 + threadIdx.x;
    if (g < 131072) {
        int kk = g >> 7, o = g & 127;
        float v = W[(size_t)kk * 128 + o];
        Bf[(((size_t)(kk >> 3) * 128) + o) * 8 + (kk & 7)] = f2bf(v);
        return;
    }
    int h = g - 131072;
    if (h < 2048) {
        int which = h >> 10;
        int r = (h >> 7) & 7;
        int i = h & 127;
        const float* vec = which ? k : q;
        const float* wrow = W + ((size_t)r * 128 + i) * 128;
        float acc = 0.f;
        #pragma unroll 4
        for (int o = 0; o < 128; o++) acc = fmaf(wrow[o], vec[o], acc);
        (which ? wk : wq)[r * 128 + i] = acc;
    }
}

// ============================ Q[n,r], K[n,r] tables: thread-per-node ============================

__global__ __launch_bounds__(256) void qk_table_kernel(const unsigned short* __restrict__ xb,
                                                       const float* __restrict__ wq,
                                                       const float* __restrict__ wk,
                                                       float* __restrict__ Q,
                                                       float* __restrict__ K, int N) {
    int n = blockIdx.x * 256 + threadIdx.x;
    if (n >= N) return;
    const uint2* row = (const uint2*)(xb + (size_t)n * 128);
    float aq[8] = {}, ak[8] = {};
    for (int i = 0; i < 32; i++) {
        uint2 d = row[i];
        float x0 = bf2f(d.x & 0xFFFFu);
        float x1 = bf2f(d.x >> 16);
        float x2 = bf2f(d.y & 0xFFFFu);
        float x3 = bf2f(d.y >> 16);
        int c = i * 4;
        #pragma unroll
        for (int r = 0; r < 8; r++) {
            const float* wqr = wq + r * 128 + c;
            const float* wkr = wk + r * 128 + c;
            aq[r] = fmaf(x0, wqr[0], fmaf(x1, wqr[1], fmaf(x2, wqr[2], fmaf(x3, wqr[3], aq[r]))));
            ak[r] = fmaf(x0, wkr[0], fmaf(x1, wkr[1], fmaf(x2, wkr[2], fmaf(x3, wkr[3], ak[r]))));
        }
    }
    float4* qp = (float4*)(Q + (size_t)n * 8);
    qp[0] = *(float4*)&aq[0];
    qp[1] = *(float4*)&aq[4];
    float4* kp = (float4*)(K + (size_t)n * 8);
    kp[0] = *(float4*)&ak[0];
    kp[1] = *(float4*)&ak[4];
}

// ============================ per-edge softmax weights (wave per node) ============================
// Node n's edges live in 8 disjoint ranges [rowp2[r*N+n], rowp2[r*N+n+1]).

__global__ __launch_bounds__(256) void weight_kernel(const float* __restrict__ Q,
                                                     const float* __restrict__ Kt,
                                                     const int* __restrict__ rowp2,
                                                     const int* __restrict__ sorted2,
                                                     float* __restrict__ alpha2, int N) {
    int wv = threadIdx.x >> 6, lane = threadIdx.x & 63;
    int n = blockIdx.x * 4 + wv;
    if (n >= N) return;
    int a0 = 0, e0 = 0;
    if (lane < 8) {
        a0 = rowp2[lane * N_NODES + n];
        e0 = rowp2[lane * N_NODES + n + 1];
    }
    int p = 0, myr = 0, myidx = 0;
    #pragma unroll
    for (int r = 0; r < 8; r++) {
        int ar = __shfl(a0, r, 64);
        int er = __shfl(e0, r, 64);
        int c = er - ar;
        if (lane >= p && lane < p + c) { myr = r; myidx = ar + lane - p; }
        p += c;
    }
    int deg = p;
    if (deg == 0) return;

    if (deg <= 64) {
        float a = -INFINITY;
        if (lane < deg) {
            int srcn = sorted2[myidx] & 0xFFFF;
            a = Q[(size_t)n * 8 + myr] + Kt[(size_t)srcn * 8 + myr];
            a = (a > 0.f) ? a : 0.2f * a;                 // leaky_relu 0.2
        }
        float m = a;
        #pragma unroll
        for (int off = 32; off; off >>= 1) m = fmaxf(m, __shfl_xor(m, off, 64));
        float e = (lane < deg) ? __expf(a - m) : 0.f;
        float sum = e;
        #pragma unroll
        for (int off = 32; off; off >>= 1) sum += __shfl_xor(sum, off, 64);
        if (lane < deg) alpha2[myidx] = e / (sum + 1e-16f);
        return;
    }

    // slow path: per-range strided passes (rare)
    float m = -INFINITY;
    #pragma unroll 1
    for (int r = 0; r < 8; r++) {
        int ar = __shfl(a0, r, 64), er = __shfl(e0, r, 64);
        for (int j = ar + lane; j < er; j += 64) {
            int srcn = sorted2[j] & 0xFFFF;
            float a = Q[(size_t)n * 8 + r] + Kt[(size_t)srcn * 8 + r];
            a = (a > 0.f) ? a : 0.2f * a;
            m = fmaxf(m, a);
        }
    }
    #pragma unroll
    for (int off = 32; off; off >>= 1) m = fmaxf(m, __shfl_xor(m, off, 64));
    float sum = 0.f;
    #pragma unroll 1
    for (int r = 0; r < 8; r++) {
        int ar = __shfl(a0, r, 64), er = __shfl(e0, r, 64);
        for (int j = ar + lane; j < er; j += 64) {
            int srcn = sorted2[j] & 0xFFFF;
            float a = Q[(size_t)n * 8 + r] + Kt[(size_t)srcn * 8 + r];
            a = (a > 0.f) ? a : 0.2f * a;
            sum += __expf(a - m);
        }
    }
    #pragma unroll
    for (int off = 32; off; off >>= 1) sum += __shfl_xor(sum, off, 64);
    float inv = 1.f / (sum + 1e-16f);
    #pragma unroll 1
    for (int r = 0; r < 8; r++) {
        int ar = __shfl(a0, r, 64), er = __shfl(e0, r, 64);
        for (int j = ar + lane; j < er; j += 64) {
            int srcn = sorted2[j] & 0xFFFF;
            float a = Q[(size_t)n * 8 + r] + Kt[(size_t)srcn * 8 + r];
            a = (a > 0.f) ? a : 0.2f * a;
            alpha2[j] = __expf(a - m) * inv;
        }
    }
}

// ============================ fused aggregate + MFMA GEMM ============================
// Block = 64 nodes, 4 waves (16 rows each). Per relation r: async-stage W_r into Bs,
// broadcast-walk the wave's contiguous edge range into LDS s-tile Sa (registers ->
// row flush), then MFMA C += Sa @ W_r. s never hits global memory.
// NOTE: xb (gather source) and hbout (feature output) must NOT alias — blocks race.

#define SA_STRIDE 136   // shorts per row: 128 + 8 pad (272 B) -> 2-way banks on rd+wr

__global__ __launch_bounds__(256) void rgat_fused(const unsigned short* __restrict__ xb,
                                                  const float* __restrict__ alpha2,
                                                  const int* __restrict__ rowp2,
                                                  const int* __restrict__ sorted2,
                                                  const short* __restrict__ Bf,
                                                  const float* __restrict__ bias,
                                                  float* __restrict__ Cout,
                                                  unsigned short* __restrict__ hbout,
                                                  int N, int relu) {
    __shared__ short Sa[64 * SA_STRIDE];          // 17408 B
    __shared__ short Bs[16 * 128 * 8];            // 32768 B
    int t = threadIdx.x;
    int wv = t >> 6, lane = t & 63;
    int lhi = lane >> 4, llo = lane & 15;
    int n0 = blockIdx.x * 64;
    const unsigned int* hbu = (const unsigned int*)xb;
    unsigned int* sap = (unsigned int*)Sa;
    f32x4 acc[8] = {};                            // rows wv*16+lhi*4.., 8 col-tiles

    for (int r = 0; r < 8; r++) {
        // async-stage B(r): 32 KB contiguous
        const char* bB = (const char*)(Bf + (size_t)r * 16384);
        #pragma unroll
        for (int i = 0; i < 8; i++) {
            __builtin_amdgcn_global_load_lds(
                (gptr_t)(bB + i * 4096 + t * 16),
                (lptr_t)((char*)Bs + i * 4096 + t * 16), 16, 0, 0);
        }
        // aggregate this wave's 16 rows (contiguous edge range; dst non-decreasing)
        int rbase = wv * 16;
        int nA = n0 + rbase;
        int iA = min(nA, N), iB = min(nA + 16, N);
        int begw = rowp2[r * N_NODES + iA];
        int endw = rowp2[r * N_NODES + iB];
        float2 a2 = {0.f, 0.f};
        int rcur = 0;
        for (int c0 = begw; c0 < endw; c0 += 64) {
            int cnt = min(64, endw - c0);
            int pk = 0; float w = 0.f;
            if (lane < cnt) {
                pk = sorted2[c0 + lane];
                w  = alpha2[c0 + lane];
            }
            for (int j = 0; j < cnt; j++) {
                int   p0 = __shfl(pk, j, 64);
                float w0 = __shfl(w,  j, 64);
                unsigned int d0 = hbu[(size_t)(p0 & 0xFFFF) * 64 + lane];
                // UNSIGNED shift: dst>=32768 sets bit 31; arithmetic >> would sign-extend.
                int row = (int)(((unsigned int)p0) >> 16) - nA;   // 0..15, non-decreasing
                while (rcur < row) {
                    sap[(size_t)(rbase + rcur) * (SA_STRIDE / 2) + lane] = packbf2(a2.x, a2.y);
                    a2.x = a2.y = 0.f; rcur++;
                }
                a2.x = fmaf(w0, bf2f(d0 & 0xFFFF), a2.x);
                a2.y = fmaf(w0, bf2f(d0 >> 16),    a2.y);
            }
        }
        while (rcur < 16) {
            sap[(size_t)(rbase + rcur) * (SA_STRIDE / 2) + lane] = packbf2(a2.x, a2.y);
            a2.x = a2.y = 0.f; rcur++;
        }
        __syncthreads();   // drains async B loads + LDS writes
        // MFMA over this relation's K=128 (16 kb, 4 chunks)
        #pragma unroll
        for (int c2 = 0; c2 < 4; c2++) {
            int kb = c2 * 4 + lhi;
            frag_t a0 = *(const frag_t*)(Sa + (size_t)(rbase + llo) * SA_STRIDE + kb * 8);
            #pragma unroll
            for (int ct = 0; ct < 8; ct++) {
                frag_t b = *(const frag_t*)(Bs + ((size_t)kb * 128 + ct * 16 + llo) * 8);
                acc[ct] = __builtin_amdgcn_mfma_f32_16x16x32_bf16(a0, b, acc[ct], 0, 0, 0);
            }
        }
        __syncthreads();   // Sa/Bs reused next relation
    }
    // epilogue: C/D layout col = llo(+16ct), row = lhi*4 + rg
    #pragma unroll
    for (int ct = 0; ct < 8; ct++) {
        int col = ct * 16 + llo;
        float bv = bias[col];
        #pragma unroll
        for (int rg = 0; rg < 4; rg++) {
            int rown = n0 + wv * 16 + lhi * 4 + rg;
            if (rown < N) {
                float v = acc[ct][rg] + bv;
                if (relu) v = fmaxf(v, 0.f);
                if (Cout)  Cout[(size_t)rown * 128 + col] = v;
                if (hbout) hbout[(size_t)rown * 128 + col] = (unsigned short)f2bf(v);
            }
        }
    }
}

// ============================ launch ============================

extern "C" void kernel_launch(void* const* d_in, const int* in_sizes, int n_in,
                              void* d_out, int out_size, void* d_ws, size_t ws_size,
                              hipStream_t stream) {
    const float* z     = (const float*)d_in[0];
    const float* lin_w = (const float*)d_in[1];
    const float* lin_b = (const float*)d_in[2];
    const float* w1    = (const float*)d_in[3];
    const float* q1    = (const float*)d_in[4];
    const float* k1    = (const float*)d_in[5];
    const float* b1    = (const float*)d_in[6];
    const float* w2    = (const float*)d_in[7];
    const float* q2    = (const float*)d_in[8];
    const float* k2    = (const float*)d_in[9];
    const float* b2    = (const float*)d_in[10];
    const int*   ei    = (const int*)d_in[11];
    const int*   et    = (const int*)d_in[12];
    float* out = (float*)d_out;

    char* ws = (char*)d_ws;
    size_t off = 0;
    auto alloc = [&](size_t bytes) -> void* {
        void* p = ws + off;
        off += (bytes + 255) & ~(size_t)255;
        return p;
    };
    unsigned short* hb  = (unsigned short*)alloc((size_t)N_NODES * 128 * 2);  // 12.8 MB (layer-0 out)
    unsigned short* hb2 = (unsigned short*)alloc((size_t)N_NODES * 128 * 2);  // 12.8 MB (layer-1 out)
    float* Q      = (float*)alloc((size_t)N_NODES * 8 * 4);
    float* K      = (float*)alloc((size_t)N_NODES * 8 * 4);
    float* alpha2 = (float*)alloc((size_t)N_EDGES * 4);
    int* sorted2  = (int*)alloc((size_t)N_EDGES * 4);
    int* deg2     = (int*)alloc((size_t)NSEG * 4);
    int* rowp2    = (int*)alloc((size_t)(NSEG + 1) * 4);
    int* cursor2  = (int*)alloc((size_t)NSEG * 4);
    int* part     = (int*)alloc(1024 * 4);
    float* wq     = (float*)alloc(8 * 128 * 4);
    float* wk     = (float*)alloc(8 * 128 * 4);
    short* Bf     = (short*)alloc((size_t)1024 * 128 * 2);      // 256 KB bf16 blocked

    const int* src = ei;
    const int* dst = ei + N_EDGES;

    const int M = NSEG;
    const int nparts = (M + 1023) / 1024;   // 391

    // CSR build over (et, dst) — relation-major
    hipMemsetAsync(deg2, 0, (size_t)M * 4, stream);
    hist_kernel<<<(N_EDGES + 255) / 256, 256, 0, stream>>>(dst, et, deg2, N_EDGES);
    scan_part<<<nparts, 256, 0, stream>>>(deg2, part, M);
    scan_mid<<<1, 512, 0, stream>>>(part, nparts, rowp2, M);
    scan_fix<<<nparts, 256, 0, stream>>>(deg2, part, rowp2, cursor2, M);
    fill_kernel<<<(N_EDGES + 255) / 256, 256, 0, stream>>>(src, dst, et, cursor2, sorted2, N_EDGES);

    // h = z @ lin_w.T + lin_b  (bf16 out only)
    gemm_lin<<<(N_NODES + 63) / 64, 256, 0, stream>>>(z, lin_w, lin_b, hb, N_NODES);

    int fgrid = (N_NODES + 63) / 64;     // 782
    int agrid = (N_NODES + 3) / 4;       // 12500
    int qgrid = (N_NODES + 255) / 256;   // 196
    int wgrid = (131072 + 2048) / 256;   // 520

    // ---- layer 1: hb -> hb2 (relu)   [double-buffered: no read/write race]
    wprep_kernel<<<wgrid, 256, 0, stream>>>(w1, q1, k1, Bf, wq, wk);
    qk_table_kernel<<<qgrid, 256, 0, stream>>>(hb, wq, wk, Q, K, N_NODES);
    weight_kernel<<<agrid, 256, 0, stream>>>(Q, K, rowp2, sorted2, alpha2, N_NODES);
    rgat_fused<<<fgrid, 256, 0, stream>>>(hb, alpha2, rowp2, sorted2, Bf, b1,
                                          (float*)nullptr, hb2, N_NODES, 1);

    // ---- layer 2: hb2 -> out (no relu)
    wprep_kernel<<<wgrid, 256, 0, stream>>>(w2, q2, k2, Bf, wq, wk);
    qk_table_kernel<<<qgrid, 256, 0, stream>>>(hb2, wq, wk, Q, K, N_NODES);
    weight_kernel<<<agrid, 256, 0, stream>>>(Q, K, rowp2, sorted2, alpha2, N_NODES);
    rgat_fused<<<fgrid, 256, 0, stream>>>(hb2, alpha2, rowp2, sorted2, Bf, b2,
                                          out, (unsigned short*)nullptr, N_NODES, 0);
}

// Round 12
// 486.036 us; speedup vs baseline: 1.4816x; 1.4816x over previous
//
#include <hip/hip_runtime.h>
#include <hip/hip_bf16.h>
#include <cstdint>
#include <cstddef>

#define N_NODES 50000
#define N_EDGES 800000
#define NSEG    (N_NODES * 8)            // 400000 (et,dst) buckets

using frag_t = __attribute__((ext_vector_type(8))) short;   // 8 bf16 (4 VGPRs)
using f32x4  = __attribute__((ext_vector_type(4))) float;   // 4 fp32 acc

typedef const __attribute__((address_space(1))) void* gptr_t;
typedef __attribute__((address_space(3))) void* lptr_t;

__device__ __forceinline__ short f2bf(float x) {
    __hip_bfloat16 h = __float2bfloat16(x);
    return *reinterpret_cast<short*>(&h);
}
__device__ __forceinline__ float bf2f(unsigned int u) {   // low 16 bits = bf16
    union { unsigned int i; float f; } v;
    v.i = u << 16;
    return v.f;
}
__device__ __forceinline__ unsigned int packbf2(float lo, float hi) {
    unsigned int a = (unsigned short)f2bf(lo);
    unsigned int b = (unsigned short)f2bf(hi);
    return a | (b << 16);
}

// ============================ CSR build over (et*N + dst) — relation-major ============================

__global__ void hist_kernel(const int* __restrict__ dst, const int* __restrict__ et,
                            int* __restrict__ deg2, int E) {
    int e = blockIdx.x * 256 + threadIdx.x;
    if (e < E) atomicAdd(&deg2[et[e] * N_NODES + dst[e]], 1);
}

__global__ __launch_bounds__(256) void scan_part(const int* __restrict__ deg2,
                                                 int* __restrict__ part, int M) {
    __shared__ int red[256];
    int t = threadIdx.x;
    int idx = blockIdx.x * 1024 + t * 4;
    int s = 0;
    if (idx + 3 < M) {
        int4 d = *(const int4*)(deg2 + idx);
        s = d.x + d.y + d.z + d.w;
    } else {
        for (int c = 0; c < 4; c++) if (idx + c < M) s += deg2[idx + c];
    }
    red[t] = s;
    __syncthreads();
    #pragma unroll
    for (int off = 128; off; off >>= 1) {
        if (t < off) red[t] += red[t + off];
        __syncthreads();
    }
    if (t == 0) part[blockIdx.x] = red[0];
}

__global__ __launch_bounds__(512) void scan_mid(int* __restrict__ part, int nparts,
                                                int* __restrict__ rowp, int M) {
    __shared__ int buf[512];
    int t = threadIdx.x;
    int own = (t < nparts) ? part[t] : 0;
    buf[t] = own;
    __syncthreads();
    for (int off = 1; off < 512; off <<= 1) {
        int v = buf[t];
        int u = (t >= off) ? buf[t - off] : 0;
        __syncthreads();
        buf[t] = v + u;
        __syncthreads();
    }
    if (t < nparts) part[t] = buf[t] - own;    // exclusive
    if (t == 511) rowp[M] = buf[511];          // total
}

__global__ __launch_bounds__(256) void scan_fix(const int* __restrict__ deg2,
                                                const int* __restrict__ part,
                                                int* __restrict__ rowp,
                                                int* __restrict__ cursor, int M) {
    __shared__ int wsum[4];
    int t = threadIdx.x, lane = t & 63, w = t >> 6;
    int idx = blockIdx.x * 1024 + t * 4;
    int v0 = 0, v1 = 0, v2 = 0, v3 = 0;
    if (idx + 3 < M) {
        int4 d = *(const int4*)(deg2 + idx);
        v0 = d.x; v1 = d.y; v2 = d.z; v3 = d.w;
    } else {
        if (idx     < M) v0 = deg2[idx];
        if (idx + 1 < M) v1 = deg2[idx + 1];
        if (idx + 2 < M) v2 = deg2[idx + 2];
        if (idx + 3 < M) v3 = deg2[idx + 3];
    }
    int tsum = v0 + v1 + v2 + v3;
    int sc = tsum;
    #pragma unroll
    for (int off = 1; off < 64; off <<= 1) {
        int u = __shfl_up(sc, off, 64);
        if (lane >= off) sc += u;
    }
    if (lane == 63) wsum[w] = sc;
    __syncthreads();
    int woff = 0;
    for (int i = 0; i < w; i++) woff += wsum[i];
    int excl = part[blockIdx.x] + woff + sc - tsum;
    if (idx     < M) { rowp[idx]     = excl; cursor[idx]     = excl; } excl += v0;
    if (idx + 1 < M) { rowp[idx + 1] = excl; cursor[idx + 1] = excl; } excl += v1;
    if (idx + 2 < M) { rowp[idx + 2] = excl; cursor[idx + 2] = excl; } excl += v2;
    if (idx + 3 < M) { rowp[idx + 3] = excl; cursor[idx + 3] = excl; }
}

// sorted2 packs src | dst<<16 (both < 65536); et implicit from position.
// NOTE: decode the dst field with an UNSIGNED shift — dst>=32768 sets the sign bit.
__global__ void fill_kernel(const int* __restrict__ src, const int* __restrict__ dst,
                            const int* __restrict__ et, int* __restrict__ cursor,
                            int* __restrict__ sorted2, int E) {
    int e = blockIdx.x * 256 + threadIdx.x;
    if (e < E) {
        int pos = atomicAdd(&cursor[et[e] * N_NODES + dst[e]], 1);
        sorted2[pos] = src[e] | (dst[e] << 16);
    }
}

// ============================ fp32 tiled GEMM (linear layer, K=64) -> bf16 hb ============================

__global__ __launch_bounds__(256) void gemm_lin(const float* __restrict__ A,
                                                const float* __restrict__ B,
                                                const float* __restrict__ bias,
                                                unsigned short* __restrict__ hb, int N) {
    const int Kdim = 64;
    __shared__ float As[32][64];
    __shared__ float Bs[32][128];
    int t = threadIdx.x;
    int n0 = blockIdx.x * 64;
    int rg = t >> 4, cg = t & 15;
    int an = t >> 2, ak = (t & 3) * 8;
    float acc[4][8] = {};

    for (int k0 = 0; k0 < Kdim; k0 += 32) {
        int gn = n0 + an;
        if (gn < N) {
            const float* ap = A + (size_t)gn * Kdim + k0 + ak;
            float4 v0 = *(const float4*)ap;
            float4 v1 = *(const float4*)(ap + 4);
            As[ak + 0][an] = v0.x; As[ak + 1][an] = v0.y;
            As[ak + 2][an] = v0.z; As[ak + 3][an] = v0.w;
            As[ak + 4][an] = v1.x; As[ak + 5][an] = v1.y;
            As[ak + 6][an] = v1.z; As[ak + 7][an] = v1.w;
        } else {
            #pragma unroll
            for (int c = 0; c < 8; c++) As[ak + c][an] = 0.f;
        }
        {
            int o = t >> 1, kh = (t & 1) * 16;
            const float* bp = B + (size_t)o * Kdim + k0 + kh;
            #pragma unroll
            for (int j = 0; j < 4; j++) {
                float4 v = ((const float4*)bp)[j];
                Bs[kh + j * 4 + 0][o] = v.x;
                Bs[kh + j * 4 + 1][o] = v.y;
                Bs[kh + j * 4 + 2][o] = v.z;
                Bs[kh + j * 4 + 3][o] = v.w;
            }
        }
        __syncthreads();
        #pragma unroll
        for (int k = 0; k < 32; k++) {
            float a[4], b[8];
            *(float4*)&a[0] = *(const float4*)&As[k][rg * 4];
            *(float4*)&b[0] = *(const float4*)&Bs[k][cg * 8];
            *(float4*)&b[4] = *(const float4*)&Bs[k][cg * 8 + 4];
            #pragma unroll
            for (int i = 0; i < 4; i++)
                #pragma unroll
                for (int j = 0; j < 8; j++)
                    acc[i][j] = fmaf(a[i], b[j], acc[i][j]);
        }
        __syncthreads();
    }
    #pragma unroll
    for (int i = 0; i < 4; i++) {
        int gn = n0 + rg * 4 + i;
        if (gn < N) {
            unsigned short us[8];
            #pragma unroll
            for (int j = 0; j < 8; j++)
                us[j] = (unsigned short)f2bf(acc[i][j] + bias[cg * 8 + j]);
            *(int4*)(hb + (size_t)gn * 128 + cg * 8) = *(int4*)&us[0];
        }
    }
}

// ============================ merged W prep: Bf convert + wq/wk ============================

__global__ void wprep_kernel(const float* __restrict__ W, const float* __restrict__ q,
                             const float* __restrict__ k, short* __restrict__ Bf,
                             float* __restrict__ wq, float* __restrict__ wk) {
    int g = blockIdx.x * 256 + threadIdx.x;
    if (g < 131072) {
        int kk = g >> 7, o = g & 127;
        float v = W[(size_t)kk * 128 + o];
        Bf[(((size_t)(kk >> 3) * 128) + o) * 8 + (kk & 7)] = f2bf(v);
        return;
    }
    int h = g - 131072;
    if (h < 2048) {
        int which = h >> 10;
        int r = (h >> 7) & 7;
        int i = h & 127;
        const float* vec = which ? k : q;
        const float* wrow = W + ((size_t)r * 128 + i) * 128;
        float acc = 0.f;
        #pragma unroll 4
        for (int o = 0; o < 128; o++) acc = fmaf(wrow[o], vec[o], acc);
        (which ? wk : wq)[r * 128 + i] = acc;
    }
}

// ============================ Q[n,r], K[n,r] tables: thread-per-node ============================

__global__ __launch_bounds__(256) void qk_table_kernel(const unsigned short* __restrict__ xb,
                                                       const float* __restrict__ wq,
                                                       const float* __restrict__ wk,
                                                       float* __restrict__ Q,
                                                       float* __restrict__ K, int N) {
    int n = blockIdx.x * 256 + threadIdx.x;
    if (n >= N) return;
    const uint2* row = (const uint2*)(xb + (size_t)n * 128);
    float aq[8] = {}, ak[8] = {};
    for (int i = 0; i < 32; i++) {
        uint2 d = row[i];
        float x0 = bf2f(d.x & 0xFFFFu);
        float x1 = bf2f(d.x >> 16);
        float x2 = bf2f(d.y & 0xFFFFu);
        float x3 = bf2f(d.y >> 16);
        int c = i * 4;
        #pragma unroll
        for (int r = 0; r < 8; r++) {
            const float* wqr = wq + r * 128 + c;
            const float* wkr = wk + r * 128 + c;
            aq[r] = fmaf(x0, wqr[0], fmaf(x1, wqr[1], fmaf(x2, wqr[2], fmaf(x3, wqr[3], aq[r]))));
            ak[r] = fmaf(x0, wkr[0], fmaf(x1, wkr[1], fmaf(x2, wkr[2], fmaf(x3, wkr[3], ak[r]))));
        }
    }
    float4* qp = (float4*)(Q + (size_t)n * 8);
    qp[0] = *(float4*)&aq[0];
    qp[1] = *(float4*)&aq[4];
    float4* kp = (float4*)(K + (size_t)n * 8);
    kp[0] = *(float4*)&ak[0];
    kp[1] = *(float4*)&ak[4];
}

// ============================ per-edge softmax weights (wave per node) ============================
// Node n's edges live in 8 disjoint ranges [rowp2[r*N+n], rowp2[r*N+n+1]).

__global__ __launch_bounds__(256) void weight_kernel(const float* __restrict__ Q,
                                                     const float* __restrict__ Kt,
                                                     const int* __restrict__ rowp2,
                                                     const int* __restrict__ sorted2,
                                                     float* __restrict__ alpha2, int N) {
    int wv = threadIdx.x >> 6, lane = threadIdx.x & 63;
    int n = blockIdx.x * 4 + wv;
    if (n >= N) return;
    int a0 = 0, e0 = 0;
    if (lane < 8) {
        a0 = rowp2[lane * N_NODES + n];
        e0 = rowp2[lane * N_NODES + n + 1];
    }
    int p = 0, myr = 0, myidx = 0;
    #pragma unroll
    for (int r = 0; r < 8; r++) {
        int ar = __shfl(a0, r, 64);
        int er = __shfl(e0, r, 64);
        int c = er - ar;
        if (lane >= p && lane < p + c) { myr = r; myidx = ar + lane - p; }
        p += c;
    }
    int deg = p;
    if (deg == 0) return;

    if (deg <= 64) {
        float a = -INFINITY;
        if (lane < deg) {
            int srcn = sorted2[myidx] & 0xFFFF;
            a = Q[(size_t)n * 8 + myr] + Kt[(size_t)srcn * 8 + myr];
            a = (a > 0.f) ? a : 0.2f * a;                 // leaky_relu 0.2
        }
        float m = a;
        #pragma unroll
        for (int off = 32; off; off >>= 1) m = fmaxf(m, __shfl_xor(m, off, 64));
        float e = (lane < deg) ? __expf(a - m) : 0.f;
        float sum = e;
        #pragma unroll
        for (int off = 32; off; off >>= 1) sum += __shfl_xor(sum, off, 64);
        if (lane < deg) alpha2[myidx] = e / (sum + 1e-16f);
        return;
    }

    // slow path: per-range strided passes (rare)
    float m = -INFINITY;
    #pragma unroll 1
    for (int r = 0; r < 8; r++) {
        int ar = __shfl(a0, r, 64), er = __shfl(e0, r, 64);
        for (int j = ar + lane; j < er; j += 64) {
            int srcn = sorted2[j] & 0xFFFF;
            float a = Q[(size_t)n * 8 + r] + Kt[(size_t)srcn * 8 + r];
            a = (a > 0.f) ? a : 0.2f * a;
            m = fmaxf(m, a);
        }
    }
    #pragma unroll
    for (int off = 32; off; off >>= 1) m = fmaxf(m, __shfl_xor(m, off, 64));
    float sum = 0.f;
    #pragma unroll 1
    for (int r = 0; r < 8; r++) {
        int ar = __shfl(a0, r, 64), er = __shfl(e0, r, 64);
        for (int j = ar + lane; j < er; j += 64) {
            int srcn = sorted2[j] & 0xFFFF;
            float a = Q[(size_t)n * 8 + r] + Kt[(size_t)srcn * 8 + r];
            a = (a > 0.f) ? a : 0.2f * a;
            sum += __expf(a - m);
        }
    }
    #pragma unroll
    for (int off = 32; off; off >>= 1) sum += __shfl_xor(sum, off, 64);
    float inv = 1.f / (sum + 1e-16f);
    #pragma unroll 1
    for (int r = 0; r < 8; r++) {
        int ar = __shfl(a0, r, 64), er = __shfl(e0, r, 64);
        for (int j = ar + lane; j < er; j += 64) {
            int srcn = sorted2[j] & 0xFFFF;
            float a = Q[(size_t)n * 8 + r] + Kt[(size_t)srcn * 8 + r];
            a = (a > 0.f) ? a : 0.2f * a;
            alpha2[j] = __expf(a - m) * inv;
        }
    }
}

// ============================ fused aggregate + MFMA GEMM ============================
// Block = 64 nodes, 4 waves (16 rows each). Per relation r: async-stage W_r into Bs,
// broadcast-walk the wave's contiguous edge range (8 gathers in flight) into LDS
// s-tile Sa, then MFMA C += Sa @ W_r. s never hits global memory.
// NOTE: xb (gather source) and hbout (feature output) must NOT alias — blocks race.

#define SA_STRIDE 136   // shorts per row: 128 + 8 pad (272 B) -> 2-way banks on rd+wr

__global__ __launch_bounds__(256) void rgat_fused(const unsigned short* __restrict__ xb,
                                                  const float* __restrict__ alpha2,
                                                  const int* __restrict__ rowp2,
                                                  const int* __restrict__ sorted2,
                                                  const short* __restrict__ Bf,
                                                  const float* __restrict__ bias,
                                                  float* __restrict__ Cout,
                                                  unsigned short* __restrict__ hbout,
                                                  int N, int relu) {
    __shared__ short Sa[64 * SA_STRIDE];          // 17408 B
    __shared__ short Bs[16 * 128 * 8];            // 32768 B
    int t = threadIdx.x;
    int wv = t >> 6, lane = t & 63;
    int lhi = lane >> 4, llo = lane & 15;
    int n0 = blockIdx.x * 64;
    const unsigned int* hbu = (const unsigned int*)xb;
    unsigned int* sap = (unsigned int*)Sa;
    f32x4 acc[8] = {};                            // rows wv*16+lhi*4.., 8 col-tiles

    for (int r = 0; r < 8; r++) {
        // async-stage B(r): 32 KB contiguous (latency hidden behind the edge walk)
        const char* bB = (const char*)(Bf + (size_t)r * 16384);
        #pragma unroll
        for (int i = 0; i < 8; i++) {
            __builtin_amdgcn_global_load_lds(
                (gptr_t)(bB + i * 4096 + t * 16),
                (lptr_t)((char*)Bs + i * 4096 + t * 16), 16, 0, 0);
        }
        // aggregate this wave's 16 rows (contiguous edge range; dst non-decreasing)
        int rbase = wv * 16;
        int nA = n0 + rbase;
        int iA = min(nA, N), iB = min(nA + 16, N);
        int begw = rowp2[r * N_NODES + iA];
        int endw = rowp2[r * N_NODES + iB];
        float2 a2 = {0.f, 0.f};
        int rcur = 0;
        for (int c0 = begw; c0 < endw; c0 += 64) {
            int cnt = min(64, endw - c0);
            int pk = 0; float w = 0.f;
            if (lane < cnt) {
                pk = sorted2[c0 + lane];
                w  = alpha2[c0 + lane];
            }
            // 8-wide batched: 8 independent gathers in flight per wave.
            // Slots j>=cnt carry pk=0,w=0: gather row 0 (valid), weight 0,
            // row-decode 0-nA <= 0 -> no flush. Harmless.
            for (int j0 = 0; j0 < cnt; j0 += 8) {
                int pp[8]; float ww[8]; unsigned int dd[8];
                #pragma unroll
                for (int i = 0; i < 8; i++) {
                    pp[i] = __shfl(pk, j0 + i, 64);
                    ww[i] = __shfl(w,  j0 + i, 64);
                }
                #pragma unroll
                for (int i = 0; i < 8; i++)
                    dd[i] = hbu[(size_t)(pp[i] & 0xFFFF) * 64 + lane];
                #pragma unroll
                for (int i = 0; i < 8; i++) {
                    // UNSIGNED shift: dst>=32768 sets bit 31.
                    int row = (int)(((unsigned int)pp[i]) >> 16) - nA;   // 0..15, non-decr
                    while (rcur < row) {
                        sap[(size_t)(rbase + rcur) * (SA_STRIDE / 2) + lane] = packbf2(a2.x, a2.y);
                        a2.x = a2.y = 0.f; rcur++;
                    }
                    a2.x = fmaf(ww[i], bf2f(dd[i] & 0xFFFF), a2.x);
                    a2.y = fmaf(ww[i], bf2f(dd[i] >> 16),    a2.y);
                }
            }
        }
        while (rcur < 16) {
            sap[(size_t)(rbase + rcur) * (SA_STRIDE / 2) + lane] = packbf2(a2.x, a2.y);
            a2.x = a2.y = 0.f; rcur++;
        }
        __syncthreads();   // drains async B loads + LDS writes
        // MFMA over this relation's K=128 (16 kb, 4 chunks)
        #pragma unroll
        for (int c2 = 0; c2 < 4; c2++) {
            int kb = c2 * 4 + lhi;
            frag_t a0 = *(const frag_t*)(Sa + (size_t)(rbase + llo) * SA_STRIDE + kb * 8);
            #pragma unroll
            for (int ct = 0; ct < 8; ct++) {
                frag_t b = *(const frag_t*)(Bs + ((size_t)kb * 128 + ct * 16 + llo) * 8);
                acc[ct] = __builtin_amdgcn_mfma_f32_16x16x32_bf16(a0, b, acc[ct], 0, 0, 0);
            }
        }
        __syncthreads();   // Sa/Bs reused next relation
    }
    // epilogue: C/D layout col = llo(+16ct), row = lhi*4 + rg
    #pragma unroll
    for (int ct = 0; ct < 8; ct++) {
        int col = ct * 16 + llo;
        float bv = bias[col];
        #pragma unroll
        for (int rg = 0; rg < 4; rg++) {
            int rown = n0 + wv * 16 + lhi * 4 + rg;
            if (rown < N) {
                float v = acc[ct][rg] + bv;
                if (relu) v = fmaxf(v, 0.f);
                if (Cout)  Cout[(size_t)rown * 128 + col] = v;
                if (hbout) hbout[(size_t)rown * 128 + col] = (unsigned short)f2bf(v);
            }
        }
    }
}

// ============================ launch ============================

extern "C" void kernel_launch(void* const* d_in, const int* in_sizes, int n_in,
                              void* d_out, int out_size, void* d_ws, size_t ws_size,
                              hipStream_t stream) {
    const float* z     = (const float*)d_in[0];
    const float* lin_w = (const float*)d_in[1];
    const float* lin_b = (const float*)d_in[2];
    const float* w1    = (const float*)d_in[3];
    const float* q1    = (const float*)d_in[4];
    const float* k1    = (const float*)d_in[5];
    const float* b1    = (const float*)d_in[6];
    const float* w2    = (const float*)d_in[7];
    const float* q2    = (const float*)d_in[8];
    const float* k2    = (const float*)d_in[9];
    const float* b2    = (const float*)d_in[10];
    const int*   ei    = (const int*)d_in[11];
    const int*   et    = (const int*)d_in[12];
    float* out = (float*)d_out;

    char* ws = (char*)d_ws;
    size_t off = 0;
    auto alloc = [&](size_t bytes) -> void* {
        void* p = ws + off;
        off += (bytes + 255) & ~(size_t)255;
        return p;
    };
    unsigned short* hb  = (unsigned short*)alloc((size_t)N_NODES * 128 * 2);  // 12.8 MB (layer-0 out)
    unsigned short* hb2 = (unsigned short*)alloc((size_t)N_NODES * 128 * 2);  // 12.8 MB (layer-1 out)
    float* Q      = (float*)alloc((size_t)N_NODES * 8 * 4);
    float* K      = (float*)alloc((size_t)N_NODES * 8 * 4);
    float* alpha2 = (float*)alloc((size_t)N_EDGES * 4);
    int* sorted2  = (int*)alloc((size_t)N_EDGES * 4);
    int* deg2     = (int*)alloc((size_t)NSEG * 4);
    int* rowp2    = (int*)alloc((size_t)(NSEG + 1) * 4);
    int* cursor2  = (int*)alloc((size_t)NSEG * 4);
    int* part     = (int*)alloc(1024 * 4);
    float* wq     = (float*)alloc(8 * 128 * 4);
    float* wk     = (float*)alloc(8 * 128 * 4);
    short* Bf     = (short*)alloc((size_t)1024 * 128 * 2);      // 256 KB bf16 blocked

    const int* src = ei;
    const int* dst = ei + N_EDGES;

    const int M = NSEG;
    const int nparts = (M + 1023) / 1024;   // 391

    // CSR build over (et, dst) — relation-major
    hipMemsetAsync(deg2, 0, (size_t)M * 4, stream);
    hist_kernel<<<(N_EDGES + 255) / 256, 256, 0, stream>>>(dst, et, deg2, N_EDGES);
    scan_part<<<nparts, 256, 0, stream>>>(deg2, part, M);
    scan_mid<<<1, 512, 0, stream>>>(part, nparts, rowp2, M);
    scan_fix<<<nparts, 256, 0, stream>>>(deg2, part, rowp2, cursor2, M);
    fill_kernel<<<(N_EDGES + 255) / 256, 256, 0, stream>>>(src, dst, et, cursor2, sorted2, N_EDGES);

    // h = z @ lin_w.T + lin_b  (bf16 out only)
    gemm_lin<<<(N_NODES + 63) / 64, 256, 0, stream>>>(z, lin_w, lin_b, hb, N_NODES);

    int fgrid = (N_NODES + 63) / 64;     // 782
    int agrid = (N_NODES + 3) / 4;       // 12500
    int qgrid = (N_NODES + 255) / 256;   // 196
    int wgrid = (131072 + 2048) / 256;   // 520

    // ---- layer 1: hb -> hb2 (relu)   [double-buffered: no read/write race]
    wprep_kernel<<<wgrid, 256, 0, stream>>>(w1, q1, k1, Bf, wq, wk);
    qk_table_kernel<<<qgrid, 256, 0, stream>>>(hb, wq, wk, Q, K, N_NODES);
    weight_kernel<<<agrid, 256, 0, stream>>>(Q, K, rowp2, sorted2, alpha2, N_NODES);
    rgat_fused<<<fgrid, 256, 0, stream>>>(hb, alpha2, rowp2, sorted2, Bf, b1,
                                          (float*)nullptr, hb2, N_NODES, 1);

    // ---- layer 2: hb2 -> out (no relu)
    wprep_kernel<<<wgrid, 256, 0, stream>>>(w2, q2, k2, Bf, wq, wk);
    qk_table_kernel<<<qgrid, 256, 0, stream>>>(hb2, wq, wk, Q, K, N_NODES);
    weight_kernel<<<agrid, 256, 0, stream>>>(Q, K, rowp2, sorted2, alpha2, N_NODES);
    rgat_fused<<<fgrid, 256, 0, stream>>>(hb2, alpha2, rowp2, sorted2, Bf, b2,
                                          out, (unsigned short*)nullptr, N_NODES, 0);
}